// Round 6
// baseline (150.637 us; speedup 1.0000x reference)
//
#include <hip/hip_runtime.h>
#include <stdint.h>

typedef unsigned long long u64;
typedef unsigned int u32;

#define NC 80
#define CONF_T 0.25f
#define IOU_THR 0.45f
#define MAX_DET 300
#define KBIG 1024
#define KSMALL 512
#define A_ANCH 8400
#define NROWS 84
#define MAX_WH 7680.0f
#define NCONF 9
#define ROLES 10

union U1 {
    u32 sc[A_ANCH];                                   // 33600 B (select phase)
    struct {                                          // post-sort phase (31184 B)
        float bx1[KBIG], by1[KBIG], bx2[KBIG], by2[KBIG], bar[KBIG];
        int keptlist[364];
        float kx1[364], ky1[364], kx2[364], ky2[364], kar[364];
        u32 kcls[364];
        u64 rows[64];
    } post;
};
union U2 {
    u32 hist[4096];                                   // 16384 B
    struct { u32 eqw[264]; u32 wpre[264]; } tie;
};

__device__ __forceinline__ float iou_f(float ix1, float iy1, float ix2, float iy2, float iar,
                                       float jx1, float jy1, float jx2, float jy2, float jar) {
    float lx = fmaxf(ix1, jx1), ly = fmaxf(iy1, jy1);
    float rx = fminf(ix2, jx2), ry = fminf(iy2, jy2);
    float ww = fmaxf(__fsub_rn(rx, lx), 0.0f);
    float hh = fmaxf(__fsub_rn(ry, ly), 0.0f);
    float inter = __fmul_rn(ww, hh);
    float den = __fadd_rn(__fsub_rn(__fadd_rn(iar, jar), inter), 1e-7f);
    return __fdiv_rn(inter, den);
}

// adaptive wave histogram add: 1 atomic for the dominant bin, per-lane for stragglers
__device__ __forceinline__ void hadd(u32* h, u32 bin, bool m, int lane) {
    u64 act = __ballot(m);
    if (act == 0) return;
    int fl = __ffsll((unsigned long long)act) - 1;
    u32 fb = __shfl(bin, fl);
    u64 same = __ballot(m && (bin == fb));
    if (lane == fl) atomicAdd(&h[fb], (u32)__popcll(same));
    if (m && (bin != fb)) atomicAdd(&h[bin], 1u);
}

// bitonic compare-exchange, partner idx^stride via shfl (stride<=32)
__device__ __forceinline__ u64 bstep(u64 v, u32 idx, u32 size, u32 stride) {
    u64 v2 = __shfl_xor((unsigned long long)v, (int)stride, 64);
    bool keep_big = (((idx & stride) == 0) == ((idx & size) == 0));
    return ((v > v2) == keep_big) ? v : v2;
}

// block-parallel descending-bin suffix select: finds bin D such that the number of
// elements in bins > D is < rem <= that + hist[D]; updates s_scal[0] |= D<<shift,
// s_scal[1] = remaining inside bin D. 512 threads.
__device__ __forceinline__ void radix_scan(u32* hist, int nb, int shift, u32* s_scal,
                                           u32* wsum, int tid, int lane, int wid) {
    int per = nb >> 9; if (per == 0) per = 1;
    int na = nb / per;
    u32 rem = s_scal[1];
    u32 Pk = s_scal[0];
    int hi = nb - 1 - per * tid;
    u32 s = 0;
    if (tid < na)
        for (int q = 0; q < per; ++q) s += hist[hi - q];
    u32 pre = s;
#pragma unroll
    for (int off = 1; off < 64; off <<= 1) {
        u32 o = __shfl_up(pre, off);
        if (lane >= off) pre += o;
    }
    if (lane == 63) wsum[wid] = pre;
    __syncthreads();
    u32 base = 0;
    for (int w = 0; w < wid; ++w) base += wsum[w];
    u32 run = base + pre - s;
    if (tid < na) {
        for (int q = 0; q < per; ++q) {
            int d = hi - q;
            u32 g = hist[d];
            if (run < rem && rem <= run + g) {
                s_scal[0] = Pk | ((u32)d << shift);
                s_scal[1] = rem - run;
            }
            run += g;
        }
    }
    __syncthreads();
}

__global__ __launch_bounds__(512, 4) void yolo_fused(const float* __restrict__ preds,
                                                     u64* __restrict__ keys,
                                                     u32* __restrict__ cnt,
                                                     float* __restrict__ out) {
    const int bid = blockIdx.x;
    const int b = bid / ROLES;
    const int role = bid % ROLES;
    const int tid = threadIdx.x;
    const int lane = tid & 63;
    const int wid = tid >> 6;

    __shared__ U1 u1;
    __shared__ U2 u2;
    __shared__ u64 skey[KBIG];
    __shared__ u32 wsum[8];
    __shared__ u32 s_scal[4];
    __shared__ u32 s_csupp[2];
    __shared__ u32 s_nkept;
    __shared__ u32 s_valid;

    if (role < NCONF) {
        // ---------- producer: conf slab (1024 anchors via float2) ----------
        int g = role * 512 + tid;
        if (g < A_ANCH / 2) {
            int a0 = g * 2;
            const float* base = preds + ((size_t)b * NROWS + 4) * A_ANCH + a0;
            float2 best = *(const float2*)base;
            int bc0 = 0, bc1 = 0;
#pragma unroll 8
            for (int c = 1; c < NC; ++c) {
                float2 v = *(const float2*)(base + (size_t)c * A_ANCH);
                if (v.x > best.x) { best.x = v.x; bc0 = c; }   // strict > = first-max argmax
                if (v.y > best.y) { best.y = v.y; bc1 = c; }
            }
            float s0 = (best.x > CONF_T) ? best.x : 0.0f;
            float s1 = (best.y > CONF_T) ? best.y : 0.0f;
            ulonglong2 kk;
            kk.x = ((u64)__float_as_uint(s0) << 32) | ((u64)(16383 - a0) << 7) | (u64)bc0;
            kk.y = ((u64)__float_as_uint(s1) << 32) | ((u64)(16383 - (a0 + 1)) << 7) | (u64)bc1;
            *(ulonglong2*)(keys + (size_t)b * A_ANCH + a0) = kk;
        }
        __threadfence();          // make key stores device-visible
        __syncthreads();
        if (tid == 0)
            __hip_atomic_fetch_add(&cnt[b], 1u, __ATOMIC_RELEASE, __HIP_MEMORY_SCOPE_AGENT);
        return;
    }

    // ---------- consumer: select + sort + NMS + emit for batch b ----------
    if (tid == 0) {
        while (__hip_atomic_load(&cnt[b], __ATOMIC_ACQUIRE, __HIP_MEMORY_SCOPE_AGENT) < NCONF)
            __builtin_amdgcn_s_sleep(2);
    }
    __syncthreads();
    __builtin_amdgcn_fence(__ATOMIC_ACQUIRE, "agent");

    const u64* kb = keys + (size_t)b * A_ANCH;

    for (int sel_pass = 0; sel_pass < 2; ++sel_pass) {
        const int K_sel = sel_pass ? KBIG : KSMALL;

        // load score bits (17 x 512 covers 8400); keep in regs AND LDS
        u32 vals[17];
#pragma unroll
        for (int it = 0; it < 17; ++it) {
            int a = tid + it * 512;
            vals[it] = (a < A_ANCH) ? (u32)(kb[a] >> 32) : 0u;
        }
        for (int i = tid; i < 4096; i += 512) u2.hist[i] = 0;
        if (tid == 0) {
            s_scal[0] = 0; s_scal[1] = (u32)K_sel; s_scal[2] = 0;
            s_nkept = 0; s_csupp[0] = 0; s_csupp[1] = 0;
            if (sel_pass == 0) s_valid = 0;
        }
#pragma unroll
        for (int it = 0; it < 17; ++it) {
            int a = tid + it * 512;
            if (a < A_ANCH) u1.sc[a] = vals[it];
        }
        __syncthreads();

        // pass 0: 12-bit hist from regs (+ valid count once)
#pragma unroll
        for (int it = 0; it < 17; ++it) {
            int a = tid + it * 512;
            hadd(u2.hist, vals[it] >> 20, a < A_ANCH, lane);
        }
        if (sel_pass == 0) {
            u32 c = 0;
#pragma unroll
            for (int it = 0; it < 17; ++it) c += (vals[it] != 0u) ? 1u : 0u;
#pragma unroll
            for (int off = 32; off >= 1; off >>= 1) c += __shfl_xor(c, off);
            if (lane == 0) atomicAdd(&s_valid, c);
        }
        __syncthreads();
        radix_scan(u2.hist, 4096, 20, s_scal, wsum, tid, lane, wid);

        // pass 1: next 12 bits among prefix-matchers
        for (int i = tid; i < 4096; i += 512) u2.hist[i] = 0;
        __syncthreads();
        u32 Pk = s_scal[0];
#pragma unroll
        for (int it = 0; it < 17; ++it) {
            int a = tid + it * 512;
            u32 v = vals[it];
            bool m = (a < A_ANCH) && ((v & 0xFFF00000u) == Pk);
            hadd(u2.hist, (v >> 8) & 4095u, m, lane);
        }
        __syncthreads();
        radix_scan(u2.hist, 4096, 8, s_scal, wsum, tid, lane, wid);

        // pass 2: final 8 bits
        for (int i = tid; i < 256; i += 512) u2.hist[i] = 0;
        __syncthreads();
        Pk = s_scal[0];
#pragma unroll
        for (int it = 0; it < 17; ++it) {
            int a = tid + it * 512;
            u32 v = vals[it];
            bool m = (a < A_ANCH) && ((v & 0xFFFFFF00u) == Pk);
            hadd(u2.hist, v & 255u, m, lane);
        }
        __syncthreads();
        radix_scan(u2.hist, 256, 0, s_scal, wsum, tid, lane, wid);

        const u32 P = s_scal[0];
        const u32 tEq = s_scal[1];   // take tEq lowest-index elements among score==P

        // tie handling: bitmask of score==P + wave0 word prefix (hist region reused)
        if (tid < 264) u2.tie.eqw[tid] = 0;
        __syncthreads();
#pragma unroll
        for (int it = 0; it < 17; ++it) {
            int a = tid + it * 512;
            if (a < A_ANCH && vals[it] == P) atomicOr(&u2.tie.eqw[a >> 5], 1u << (a & 31));
        }
        __syncthreads();
        if (wid == 0) {
            u32 cw[5], loc = 0;
#pragma unroll
            for (int q = 0; q < 5; ++q) {
                int w2 = lane * 5 + q;
                u32 e = (w2 < 264) ? u2.tie.eqw[w2] : 0u;
                cw[q] = (u32)__popc(e); loc += cw[q];
            }
            u32 pre = loc;
#pragma unroll
            for (int off = 1; off < 64; off <<= 1) {
                u32 o = __shfl_up(pre, off);
                if (lane >= off) pre += o;
            }
            u32 run = pre - loc;
#pragma unroll
            for (int q = 0; q < 5; ++q) {
                int w2 = lane * 5 + q;
                if (w2 < 264) u2.tie.wpre[w2] = run;
                run += cw[q];
            }
        }
        __syncthreads();

        // compaction: exactly K_sel keys -> skey (unsorted; sort follows)
#pragma unroll
        for (int it = 0; it < 17; ++it) {
            int a = tid + it * 512;
            bool take = false;
            if (a < A_ANCH) {
                u32 v = vals[it];
                take = v > P;
                if (!take && v == P) {
                    u32 r = u2.tie.wpre[a >> 5] +
                            (u32)__popc(u2.tie.eqw[a >> 5] & ((1u << (a & 31)) - 1u));
                    take = (r < tEq);
                }
            }
            u64 m = __ballot(take);
            if (m) {
                int fl = __ffsll((unsigned long long)m) - 1;
                u32 basep = 0;
                if (lane == fl) basep = atomicAdd(&s_scal[2], (u32)__popcll(m));
                basep = __shfl(basep, fl);
                if (take) skey[basep + (u32)__popcll(m & ((1ull << lane) - 1ull))] = kb[a];
            }
        }
        __syncthreads();

        // ---- bitonic sort descending (keys unique -> deterministic) ----
        if (K_sel == KSMALL) {
            u64 v = skey[tid];
#pragma unroll
            for (u32 size = 2; size <= 64; size <<= 1)
#pragma unroll
                for (u32 stride = size >> 1; stride >= 1; stride >>= 1)
                    v = bstep(v, (u32)tid, size, stride);
            for (u32 size = 128; size <= 512; size <<= 1) {
                for (u32 stride = size >> 1; stride >= 64; stride >>= 1) {
                    skey[tid] = v; __syncthreads();
                    u64 v2 = skey[tid ^ stride];
                    bool keep_big = ((((u32)tid & stride) == 0) == (((u32)tid & size) == 0));
                    v = ((v > v2) == keep_big) ? v : v2;
                    __syncthreads();
                }
#pragma unroll
                for (u32 stride = 32; stride >= 1; stride >>= 1)
                    v = bstep(v, (u32)tid, size, stride);
            }
            skey[tid] = v;
            __syncthreads();
        } else {
            u64 vA = skey[tid], vB = skey[tid + 512];
            const u32 iA = (u32)tid, iB = (u32)tid + 512;
#pragma unroll
            for (u32 size = 2; size <= 64; size <<= 1)
#pragma unroll
                for (u32 stride = size >> 1; stride >= 1; stride >>= 1) {
                    vA = bstep(vA, iA, size, stride);
                    vB = bstep(vB, iB, size, stride);
                }
            skey[tid] = vA; skey[tid + 512] = vB;
            __syncthreads();
            for (u32 size = 128; size <= 1024; size <<= 1) {
                for (u32 stride = size >> 1; stride >= 64; stride >>= 1) {
                    u32 i1 = ((tid & ~(int)(stride - 1)) << 1) | (tid & (stride - 1));
                    u32 i2 = i1 + stride;
                    bool desc = ((i1 & size) == 0);
                    u64 x = skey[i1], y = skey[i2];
                    if ((x < y) == desc) { skey[i1] = y; skey[i2] = x; }
                    __syncthreads();
                }
                vA = skey[tid]; vB = skey[tid + 512];
#pragma unroll
                for (u32 stride = 32; stride >= 1; stride >>= 1) {
                    vA = bstep(vA, iA, size, stride);
                    vB = bstep(vB, iB, size, stride);
                }
                skey[tid] = vA; skey[tid + 512] = vB;
                __syncthreads();
            }
        }

        // ---- offset boxes (overlay onto sc region) ----
        for (int t = tid; t < K_sel; t += 512) {
            u64 key = skey[t];
            int cls = (int)(key & 127u);
            int idx = 16383 - (int)((key >> 7) & 16383u);
            const float* pb = preds + (size_t)b * NROWS * A_ANCH + idx;
            float x = pb[0];
            float y = pb[A_ANCH];
            float w = pb[2 * A_ANCH];
            float h = pb[3 * A_ANCH];
            float hw = __fmul_rn(w, 0.5f), hh = __fmul_rn(h, 0.5f);
            float x1 = __fsub_rn(x, hw), x2 = __fadd_rn(x, hw);
            float y1 = __fsub_rn(y, hh), y2 = __fadd_rn(y, hh);
            float off = __fmul_rn((float)cls, MAX_WH);
            float bx1 = __fadd_rn(x1, off), bx2 = __fadd_rn(x2, off);
            float by1 = __fadd_rn(y1, off), by2 = __fadd_rn(y2, off);
            u1.post.bx1[t] = bx1; u1.post.by1[t] = by1;
            u1.post.bx2[t] = bx2; u1.post.by2[t] = by2;
            u1.post.bar[t] = __fmul_rn(__fsub_rn(bx2, bx1), __fsub_rn(by2, by1)); // area of OFFSET box
        }
        __syncthreads();

        // ---- greedy NMS over chunks of 64 ----
        const int nchunks = K_sel / 64;
        for (int c = 0; c < nchunks; ++c) {
            int j = c * 64 + lane;
            u64 keyj = skey[j];
            float scj = __uint_as_float((u32)(keyj >> 32));
            u32 clsj = (u32)(keyj & 127u);
            float jx1 = u1.post.bx1[j], jy1 = u1.post.by1[j];
            float jx2 = u1.post.bx2[j], jy2 = u1.post.by2[j], jar = u1.post.bar[j];

            // Phase A: chunk vs compact kept list (8 waves strided)
            u32 nk = s_nkept;
            bool suppbit = false;
            for (u32 k = wid; k < nk; k += 8) {
                bool cm = (u1.post.kcls[k] == clsj);
                if (__ballot(cm)) {   // cross-class IoU exactly 0 (7680 offset)
                    float iou = iou_f(u1.post.kx1[k], u1.post.ky1[k], u1.post.kx2[k],
                                      u1.post.ky2[k], u1.post.kar[k],
                                      jx1, jy1, jx2, jy2, jar);
                    suppbit |= (cm && (iou > IOU_THR));
                }
            }
            u64 bm = __ballot(suppbit);
            if (bm && lane == 0) {
                atomicOr(&s_csupp[0], (u32)bm);
                atomicOr(&s_csupp[1], (u32)(bm >> 32));
            }

            // Phase B: in-chunk 64x64 suppression matrix, 8 rows per wave
#pragma unroll
            for (int p2 = 0; p2 < 8; ++p2) {
                int i = p2 * 8 + wid;
                int ci = c * 64 + i;
                u32 clsi = (u32)(skey[ci] & 127u);
                u64 m = 0;
                if (__ballot(clsi == clsj)) {
                    float iou = iou_f(u1.post.bx1[ci], u1.post.by1[ci], u1.post.bx2[ci],
                                      u1.post.by2[ci], u1.post.bar[ci],
                                      jx1, jy1, jx2, jy2, jar);
                    m = __ballot((lane > i) && (iou > IOU_THR));
                }
                if (lane == 0) u1.post.rows[i] = m;
            }
            __syncthreads();

            // Phase C: wave-0 scalar greedy recurrence
            if (wid == 0) {
                u64 row = u1.post.rows[lane];
                u32 rlo = (u32)row, rhi = (u32)(row >> 32);
                u64 csupp = (((u64)s_csupp[1]) << 32) | (u64)s_csupp[0];
                u64 validm = __ballot(scj > CONF_T) & ~csupp;
                u64 supp = 0, keep = 0;
#pragma unroll
                for (int i = 0; i < 64; ++i) {
                    u64 ri = (((u64)(u32)__builtin_amdgcn_readlane((int)rhi, i)) << 32) |
                             (u64)(u32)__builtin_amdgcn_readlane((int)rlo, i);
                    bool ki = (((validm & ~supp) >> i) & 1ull) != 0;
                    if (ki) { keep |= (1ull << i); supp |= ri; }
                }
                u32 basek = s_nkept;
                if ((keep >> lane) & 1ull) {
                    u32 slot = basek + (u32)__popcll(keep & ((1ull << lane) - 1ull));
                    u1.post.keptlist[slot] = j;
                    u1.post.kx1[slot] = jx1; u1.post.ky1[slot] = jy1;
                    u1.post.kx2[slot] = jx2; u1.post.ky2[slot] = jy2;
                    u1.post.kar[slot] = jar; u1.post.kcls[slot] = clsj;
                }
                if (lane == 0) {
                    s_nkept = basek + (u32)__popcll(keep);
                    s_csupp[0] = 0; s_csupp[1] = 0;
                }
            }
            __syncthreads();
            if (s_nkept >= MAX_DET) break;   // forward-only suppression: first 300 fixed
        }

        u32 nk = s_nkept;
        bool finished = (nk >= MAX_DET) || (s_valid <= (u32)K_sel) || (sel_pass == 1);
        if (!finished) continue;   // exact fallback with K=1024 (never taken on bench data)

        // ---- emit ----
        if (tid < MAX_DET) {
            float row[6];
            int t = (tid < (int)(nk < MAX_DET ? nk : MAX_DET)) ? u1.post.keptlist[tid] : -1;
            if (t >= 0) {
                u64 key = skey[t];
                float score = __uint_as_float((u32)(key >> 32));
                int cls = (int)(key & 127u);
                int idx = 16383 - (int)((key >> 7) & 16383u);
                const float* pb = preds + (size_t)b * NROWS * A_ANCH + idx;
                float x = pb[0], y = pb[A_ANCH], w = pb[2 * A_ANCH], h = pb[3 * A_ANCH];
                float hw = __fmul_rn(w, 0.5f), hh = __fmul_rn(h, 0.5f);
                row[0] = __fsub_rn(x, hw);
                row[1] = __fsub_rn(y, hh);
                row[2] = __fadd_rn(x, hw);
                row[3] = __fadd_rn(y, hh);
                row[4] = score;
                row[5] = (float)cls;
            } else {
                row[0] = row[1] = row[2] = row[3] = row[4] = row[5] = (float)NC;
            }
            float* o = out + ((size_t)b * MAX_DET + tid) * 6;
#pragma unroll
            for (int q = 0; q < 6; ++q) o[q] = row[q];
        }
        break;
    }
}

extern "C" void kernel_launch(void* const* d_in, const int* in_sizes, int n_in,
                              void* d_out, int out_size, void* d_ws, size_t ws_size,
                              hipStream_t stream) {
    const float* preds = (const float*)d_in[0];
    float* out = (float*)d_out;
    int B = in_sizes[0] / (NROWS * A_ANCH);
    u64* keys = (u64*)d_ws;                       // B*8400 u64
    u32* cnt = (u32*)(keys + (size_t)B * A_ANCH); // B u32 arrival counters
    (void)hipMemsetAsync(cnt, 0, (size_t)B * sizeof(u32), stream);
    yolo_fused<<<dim3(B * ROLES), dim3(512), 0, stream>>>(preds, keys, cnt, out);
}

// Round 7
// 73.768 us; speedup vs baseline: 2.0420x; 2.0420x over previous
//
#include <hip/hip_runtime.h>
#include <stdint.h>

typedef unsigned long long u64;
typedef unsigned int u32;

#define NC 80
#define CONF_T 0.25f
#define IOU_THR 0.45f
#define MAX_DET 300
#define KBIG 1024
#define KSMALL 512
#define A_ANCH 8400
#define NROWS 84
#define MAX_WH 7680.0f

// ---------------- Kernel 1: per-anchor class max/argmax -> packed sort key ----------------
// key = (score_bits << 32) | ((16383 - anchor) << 7) | cls
// Descending u64 == descending score, ties by ascending anchor (top_k tie-break).
__global__ __launch_bounds__(256) void yolo_conf_kernel(const float* __restrict__ preds,
                                                        u64* __restrict__ keys) {
    int b = blockIdx.x / 9;
    int g = (blockIdx.x % 9) * 256 + threadIdx.x;   // float4 group of 4 anchors
    if (g >= A_ANCH / 4) return;
    int a0 = g * 4;
    const float* base = preds + ((size_t)b * NROWS + 4) * A_ANCH + a0;
    float4 best = *(const float4*)base;
    int bcx = 0, bcy = 0, bcz = 0, bcw = 0;
#pragma unroll 4
    for (int c = 1; c < NC; ++c) {
        float4 v = *(const float4*)(base + (size_t)c * A_ANCH);
        if (v.x > best.x) { best.x = v.x; bcx = c; }   // strict > = first-max argmax
        if (v.y > best.y) { best.y = v.y; bcy = c; }
        if (v.z > best.z) { best.z = v.z; bcz = c; }
        if (v.w > best.w) { best.w = v.w; bcw = c; }
    }
    float s0 = (best.x > CONF_T) ? best.x : 0.0f;
    float s1 = (best.y > CONF_T) ? best.y : 0.0f;
    float s2 = (best.z > CONF_T) ? best.z : 0.0f;
    float s3 = (best.w > CONF_T) ? best.w : 0.0f;
    u64* ko = keys + (size_t)b * A_ANCH + a0;
    ulonglong2 k01, k23;
    k01.x = ((u64)__float_as_uint(s0) << 32) | ((u64)(16383 - a0) << 7) | (u64)bcx;
    k01.y = ((u64)__float_as_uint(s1) << 32) | ((u64)(16383 - (a0 + 1)) << 7) | (u64)bcy;
    k23.x = ((u64)__float_as_uint(s2) << 32) | ((u64)(16383 - (a0 + 2)) << 7) | (u64)bcz;
    k23.y = ((u64)__float_as_uint(s3) << 32) | ((u64)(16383 - (a0 + 3)) << 7) | (u64)bcw;
    *(ulonglong2*)ko = k01;
    *(ulonglong2*)(ko + 2) = k23;
}

__device__ __forceinline__ float iou_f(float ix1, float iy1, float ix2, float iy2, float iar,
                                       float jx1, float jy1, float jx2, float jy2, float jar) {
    float lx = fmaxf(ix1, jx1), ly = fmaxf(iy1, jy1);
    float rx = fminf(ix2, jx2), ry = fminf(iy2, jy2);
    float ww = fmaxf(__fsub_rn(rx, lx), 0.0f);
    float hh = fmaxf(__fsub_rn(ry, ly), 0.0f);
    float inter = __fmul_rn(ww, hh);
    float den = __fadd_rn(__fsub_rn(__fadd_rn(iar, jar), inter), 1e-7f);
    return __fdiv_rn(inter, den);
}

// adaptive wave histogram add: 1 atomic for the dominant bin, per-lane for stragglers
__device__ __forceinline__ void hadd(u32* h, u32 bin, bool m, int lane) {
    u64 act = __ballot(m);
    if (act == 0) return;
    int fl = __ffsll((unsigned long long)act) - 1;
    u32 fb = __shfl(bin, fl);
    u64 same = __ballot(m && (bin == fb));
    if (lane == fl) atomicAdd(&h[fb], (u32)__popcll(same));
    if (m && (bin != fb)) atomicAdd(&h[bin], 1u);
}

// bitonic compare-exchange, partner idx^stride via shfl (stride<=32)
__device__ __forceinline__ u64 bstep(u64 v, u32 idx, u32 size, u32 stride) {
    u64 v2 = __shfl_xor((unsigned long long)v, (int)stride, 64);
    bool keep_big = (((idx & stride) == 0) == ((idx & size) == 0));
    return ((v > v2) == keep_big) ? v : v2;
}

// block-parallel descending-bin suffix select over hist (1024 threads):
// finds bin D with (count in bins > D) < rem <= (that + hist[D]);
// s_scal[0] |= D<<shift, s_scal[1] = remaining inside bin D.
__device__ __forceinline__ void radix_scan(u32* hist, int nb, int shift, u32* s_scal,
                                           u32* wsum, int tid, int lane, int wid) {
    int per = nb >> 10; if (per == 0) per = 1;
    int na = nb / per;
    u32 rem = s_scal[1];
    u32 Pk = s_scal[0];
    int hi = nb - 1 - per * tid;
    u32 s = 0;
    if (tid < na)
        for (int q = 0; q < per; ++q) s += hist[hi - q];
    u32 pre = s;
#pragma unroll
    for (int off = 1; off < 64; off <<= 1) {
        u32 o = __shfl_up(pre, off);
        if (lane >= off) pre += o;
    }
    if (lane == 63) wsum[wid] = pre;
    __syncthreads();
    u32 base = 0;
    for (int w = 0; w < wid; ++w) base += wsum[w];
    u32 run = base + pre - s;
    if (tid < na) {
        for (int q = 0; q < per; ++q) {
            int d = hi - q;
            u32 g = hist[d];
            if (run < rem && rem <= run + g) {
                s_scal[0] = Pk | ((u32)d << shift);
                s_scal[1] = rem - run;
            }
            run += g;
        }
    }
    __syncthreads();
}

union U2 {
    u32 hist[4096];                                   // 16384 B
    struct { u32 eqw[264]; u32 wpre[264]; } tie;
};

// ---------------- Kernel 2: top-K select + sort + greedy NMS + emit (one block/batch) ----------------
__global__ __launch_bounds__(1024) void yolo_nms_kernel(const float* __restrict__ preds,
                                                        const u64* __restrict__ keys,
                                                        float* __restrict__ out) {
    const int b = blockIdx.x;
    const int tid = threadIdx.x;
    const int lane = tid & 63;
    const int wid = tid >> 6;   // 0..15

    __shared__ U2 u2;
    __shared__ u64 skey[KBIG];                        // 8192 B
    __shared__ float BX1[KBIG], BY1[KBIG], BX2[KBIG], BY2[KBIG], BAR[KBIG];  // 20480 B
    __shared__ int keptlist[364];
    __shared__ float kx1[364], ky1[364], kx2[364], ky2[364], kar[364];
    __shared__ u32 kcls[364];
    __shared__ u64 rows[64];
    __shared__ u32 wsum[16];
    __shared__ u32 s_scal[4];                         // 0: P bits, 1: k-remaining, 2: compact cnt
    __shared__ u32 s_csupp[2];
    __shared__ u32 s_nkept;
    __shared__ u32 s_valid;

    const u64* kb = keys + (size_t)b * A_ANCH;

    // score bits live in registers for all scans (9 x 1024 covers 8400)
    u32 vals[9];
#pragma unroll
    for (int it = 0; it < 9; ++it) {
        int a = tid + it * 1024;
        vals[it] = (a < A_ANCH) ? (u32)(kb[a] >> 32) : 0u;
    }

    for (int sel_pass = 0; sel_pass < 2; ++sel_pass) {
        const int K_sel = sel_pass ? KBIG : KSMALL;

        for (int i = tid; i < 4096; i += 1024) u2.hist[i] = 0;
        if (tid == 0) {
            s_scal[0] = 0; s_scal[1] = (u32)K_sel; s_scal[2] = 0;
            s_nkept = 0; s_csupp[0] = 0; s_csupp[1] = 0;
            if (sel_pass == 0) s_valid = 0;
        }
        __syncthreads();

        // pass 0: top 12 bits [31:20] (+ valid count once)
#pragma unroll
        for (int it = 0; it < 9; ++it) {
            int a = tid + it * 1024;
            hadd(u2.hist, vals[it] >> 20, a < A_ANCH, lane);
        }
        if (sel_pass == 0) {
            u32 c = 0;
#pragma unroll
            for (int it = 0; it < 9; ++it) c += (vals[it] != 0u) ? 1u : 0u;
#pragma unroll
            for (int off = 32; off >= 1; off >>= 1) c += __shfl_xor(c, off);
            if (lane == 0) atomicAdd(&s_valid, c);
        }
        __syncthreads();
        radix_scan(u2.hist, 4096, 20, s_scal, wsum, tid, lane, wid);

        // pass 1: bits [19:8] among prefix-matchers
        for (int i = tid; i < 4096; i += 1024) u2.hist[i] = 0;
        __syncthreads();
        u32 Pk = s_scal[0];
#pragma unroll
        for (int it = 0; it < 9; ++it) {
            int a = tid + it * 1024;
            u32 v = vals[it];
            bool m = (a < A_ANCH) && ((v & 0xFFF00000u) == Pk);
            hadd(u2.hist, (v >> 8) & 4095u, m, lane);
        }
        __syncthreads();
        radix_scan(u2.hist, 4096, 8, s_scal, wsum, tid, lane, wid);

        // pass 2: bits [7:0]
        for (int i = tid; i < 256; i += 1024) u2.hist[i] = 0;
        __syncthreads();
        Pk = s_scal[0];
#pragma unroll
        for (int it = 0; it < 9; ++it) {
            int a = tid + it * 1024;
            u32 v = vals[it];
            bool m = (a < A_ANCH) && ((v & 0xFFFFFF00u) == Pk);
            hadd(u2.hist, v & 255u, m, lane);
        }
        __syncthreads();
        radix_scan(u2.hist, 256, 0, s_scal, wsum, tid, lane, wid);

        const u32 P = s_scal[0];
        const u32 tEq = s_scal[1];   // take tEq lowest-index elements among score==P

        // tie handling: bitmask of score==P + wave0 word prefix (hist region reused)
        if (tid < 264) u2.tie.eqw[tid] = 0;
        __syncthreads();
#pragma unroll
        for (int it = 0; it < 9; ++it) {
            int a = tid + it * 1024;
            if (a < A_ANCH && vals[it] == P) atomicOr(&u2.tie.eqw[a >> 5], 1u << (a & 31));
        }
        __syncthreads();
        if (wid == 0) {
            u32 cw[5], loc = 0;
#pragma unroll
            for (int q = 0; q < 5; ++q) {
                int w2 = lane * 5 + q;
                u32 e = (w2 < 264) ? u2.tie.eqw[w2] : 0u;
                cw[q] = (u32)__popc(e); loc += cw[q];
            }
            u32 pre = loc;
#pragma unroll
            for (int off = 1; off < 64; off <<= 1) {
                u32 o = __shfl_up(pre, off);
                if (lane >= off) pre += o;
            }
            u32 run = pre - loc;
#pragma unroll
            for (int q = 0; q < 5; ++q) {
                int w2 = lane * 5 + q;
                if (w2 < 264) u2.tie.wpre[w2] = run;
                run += cw[q];
            }
        }
        __syncthreads();

        // compaction: exactly K_sel keys -> skey (unsorted; sort follows)
#pragma unroll
        for (int it = 0; it < 9; ++it) {
            int a = tid + it * 1024;
            bool take = false;
            if (a < A_ANCH) {
                u32 v = vals[it];
                take = v > P;
                if (!take && v == P) {
                    u32 r = u2.tie.wpre[a >> 5] +
                            (u32)__popc(u2.tie.eqw[a >> 5] & ((1u << (a & 31)) - 1u));
                    take = (r < tEq);
                }
            }
            u64 m = __ballot(take);
            if (m) {
                int fl = __ffsll((unsigned long long)m) - 1;
                u32 basep = 0;
                if (lane == fl) basep = atomicAdd(&s_scal[2], (u32)__popcll(m));
                basep = __shfl(basep, fl);
                if (take) skey[basep + (u32)__popcll(m & ((1ull << lane) - 1ull))] = kb[a];
            }
        }
        __syncthreads();

        // ---- hybrid bitonic sort descending, 1 elem/thread, active = tid < K_sel ----
        {
            const bool act = tid < K_sel;
            u64 v = act ? skey[tid] : 0;
            if (act) {
#pragma unroll
                for (u32 size = 2; size <= 64; size <<= 1)
#pragma unroll
                    for (u32 stride = size >> 1; stride >= 1; stride >>= 1)
                        v = bstep(v, (u32)tid, size, stride);
            }
            for (u32 size = 128; size <= (u32)K_sel; size <<= 1) {
                for (u32 stride = size >> 1; stride >= 64; stride >>= 1) {
                    if (act) skey[tid] = v;
                    __syncthreads();
                    if (act) {
                        u64 v2 = skey[tid ^ stride];
                        bool keep_big = ((((u32)tid & stride) == 0) == (((u32)tid & size) == 0));
                        v = ((v > v2) == keep_big) ? v : v2;
                    }
                    __syncthreads();
                }
                if (act) {
#pragma unroll
                    for (u32 stride = 32; stride >= 1; stride >>= 1)
                        v = bstep(v, (u32)tid, size, stride);
                }
            }
            if (act) skey[tid] = v;
            __syncthreads();
        }

        // ---- offset boxes ----
        if (tid < K_sel) {
            u64 key = skey[tid];
            int cls = (int)(key & 127u);
            int idx = 16383 - (int)((key >> 7) & 16383u);
            const float* pb = preds + (size_t)b * NROWS * A_ANCH + idx;
            float x = pb[0];
            float y = pb[A_ANCH];
            float w = pb[2 * A_ANCH];
            float h = pb[3 * A_ANCH];
            float hw = __fmul_rn(w, 0.5f), hh = __fmul_rn(h, 0.5f);
            float x1 = __fsub_rn(x, hw), x2 = __fadd_rn(x, hw);
            float y1 = __fsub_rn(y, hh), y2 = __fadd_rn(y, hh);
            float off = __fmul_rn((float)cls, MAX_WH);
            float bx1 = __fadd_rn(x1, off), bx2 = __fadd_rn(x2, off);
            float by1 = __fadd_rn(y1, off), by2 = __fadd_rn(y2, off);
            BX1[tid] = bx1; BY1[tid] = by1; BX2[tid] = bx2; BY2[tid] = by2;
            BAR[tid] = __fmul_rn(__fsub_rn(bx2, bx1), __fsub_rn(by2, by1)); // area of OFFSET box, as reference
        }
        __syncthreads();

        // ---- greedy NMS over chunks of 64 ----
        const int nchunks = K_sel / 64;
        for (int c = 0; c < nchunks; ++c) {
            int j = c * 64 + lane;
            u64 keyj = skey[j];
            float scj = __uint_as_float((u32)(keyj >> 32));
            u32 clsj = (u32)(keyj & 127u);
            float jx1 = BX1[j], jy1 = BY1[j], jx2 = BX2[j], jy2 = BY2[j], jar = BAR[j];

            // Phase A: chunk vs compact kept list (16 waves strided)
            u32 nk = s_nkept;
            bool suppbit = false;
            for (u32 k = wid; k < nk; k += 16) {
                bool cm = (kcls[k] == clsj);
                if (__ballot(cm)) {   // cross-class IoU exactly 0 (7680 offset)
                    float iou = iou_f(kx1[k], ky1[k], kx2[k], ky2[k], kar[k],
                                      jx1, jy1, jx2, jy2, jar);
                    suppbit |= (cm && (iou > IOU_THR));
                }
            }
            u64 bm = __ballot(suppbit);
            if (bm && lane == 0) {
                atomicOr(&s_csupp[0], (u32)bm);
                atomicOr(&s_csupp[1], (u32)(bm >> 32));
            }

            // Phase B: in-chunk 64x64 suppression matrix, 4 rows per wave
#pragma unroll
            for (int p2 = 0; p2 < 4; ++p2) {
                int i = p2 * 16 + wid;
                int ci = c * 64 + i;
                u32 clsi = (u32)(skey[ci] & 127u);
                u64 m = 0;
                if (__ballot(clsi == clsj)) {
                    float iou = iou_f(BX1[ci], BY1[ci], BX2[ci], BY2[ci], BAR[ci],
                                      jx1, jy1, jx2, jy2, jar);
                    m = __ballot((lane > i) && (iou > IOU_THR));
                }
                if (lane == 0) rows[i] = m;
            }
            __syncthreads();

            // Phase C: wave-0 scalar greedy recurrence (readlane -> SGPR chain)
            if (wid == 0) {
                u64 row = rows[lane];
                u32 rlo = (u32)row, rhi = (u32)(row >> 32);
                u64 csupp = (((u64)s_csupp[1]) << 32) | (u64)s_csupp[0];
                u64 validm = __ballot(scj > CONF_T) & ~csupp;
                u64 supp = 0, keep = 0;
#pragma unroll
                for (int i = 0; i < 64; ++i) {
                    u64 ri = (((u64)(u32)__builtin_amdgcn_readlane((int)rhi, i)) << 32) |
                             (u64)(u32)__builtin_amdgcn_readlane((int)rlo, i);
                    bool ki = (((validm & ~supp) >> i) & 1ull) != 0;
                    if (ki) { keep |= (1ull << i); supp |= ri; }
                }
                u32 basek = s_nkept;
                if ((keep >> lane) & 1ull) {
                    u32 slot = basek + (u32)__popcll(keep & ((1ull << lane) - 1ull));
                    keptlist[slot] = j;
                    kx1[slot] = jx1; ky1[slot] = jy1;
                    kx2[slot] = jx2; ky2[slot] = jy2;
                    kar[slot] = jar; kcls[slot] = clsj;
                }
                if (lane == 0) {
                    s_nkept = basek + (u32)__popcll(keep);
                    s_csupp[0] = 0; s_csupp[1] = 0;
                }
            }
            __syncthreads();
            if (s_nkept >= MAX_DET) break;   // forward-only suppression: first 300 fixed
        }

        u32 nk = s_nkept;
        // exact fallback with K=1024 only if needed (never taken on bench data)
        bool finished = (nk >= MAX_DET) || (s_valid <= (u32)K_sel) || (sel_pass == 1);
        if (!finished) { __syncthreads(); continue; }

        // ---- emit ----
        if (tid < MAX_DET) {
            float row[6];
            int t = (tid < (int)(nk < MAX_DET ? nk : MAX_DET)) ? keptlist[tid] : -1;
            if (t >= 0) {
                u64 key = skey[t];
                float score = __uint_as_float((u32)(key >> 32));
                int cls = (int)(key & 127u);
                int idx = 16383 - (int)((key >> 7) & 16383u);
                const float* pb = preds + (size_t)b * NROWS * A_ANCH + idx;
                float x = pb[0], y = pb[A_ANCH], w = pb[2 * A_ANCH], h = pb[3 * A_ANCH];
                float hw = __fmul_rn(w, 0.5f), hh = __fmul_rn(h, 0.5f);
                row[0] = __fsub_rn(x, hw);
                row[1] = __fsub_rn(y, hh);
                row[2] = __fadd_rn(x, hw);
                row[3] = __fadd_rn(y, hh);
                row[4] = score;
                row[5] = (float)cls;
            } else {
                row[0] = row[1] = row[2] = row[3] = row[4] = row[5] = (float)NC;
            }
            float* o = out + ((size_t)b * MAX_DET + tid) * 6;
#pragma unroll
            for (int q = 0; q < 6; ++q) o[q] = row[q];
        }
        break;
    }
}

extern "C" void kernel_launch(void* const* d_in, const int* in_sizes, int n_in,
                              void* d_out, int out_size, void* d_ws, size_t ws_size,
                              hipStream_t stream) {
    const float* preds = (const float*)d_in[0];
    float* out = (float*)d_out;
    u64* keys = (u64*)d_ws;   // B * 8400 u64 ~= 2.1 MB
    int B = in_sizes[0] / (NROWS * A_ANCH);
    yolo_conf_kernel<<<dim3(B * 9), dim3(256), 0, stream>>>(preds, keys);
    yolo_nms_kernel<<<dim3(B), dim3(1024), 0, stream>>>(preds, keys, out);
}